// Round 12
// baseline (328.880 us; speedup 1.0000x reference)
//
#include <hip/hip_runtime.h>
#include <cstdint>
#include <cstddef>

// ---------------------------------------------------------------------------
// TWLayer — all-MFMA pipeline.
//   K1:  R17 config (barrier-free own-slice stages, direct S stores).
//   K2:  R22 — 2-slot 48 KB LDS (was 3-slot 72 KB) -> 3 blocks/CU.
//        R12 ledger: per-phase MFMA + LDS-read are additive in-wave; 2
//        blocks/CU recovered only part (MfmaUtil 41%). LDS was the binding
//        residency constraint (VGPR 116 allows 4 waves/SIMD). Depth-1
//        pipeline: stage region p+1 at phase-p start; vmcnt(0) ~1400+ cyc
//        later covers HBM ~900 cyc; 3rd block fills residual stalls.
//        Slot safety: slot (p+1)%2 last read in phase p-1, sealed by that
//        barrier. One barrier/phase, unchanged. Output bit-identical.
//   K3:  R21 in-place 20 KB + plain partial stores (dropped out of top-5).
//   K4:  R21 f64 reduce + bias — DETERMINISTIC absmax 1.887e7 (passed);
//        numerics FROZEN (atomics re-rolled ordering per replay, R20 fail).
// ---------------------------------------------------------------------------

typedef __attribute__((ext_vector_type(8))) short short8;   // 8 x bf16
typedef __attribute__((ext_vector_type(4))) float f32x4;

static __device__ __forceinline__ unsigned short f2bf(float f) {
  union { float f; unsigned int u; } v; v.f = f;
  unsigned int r = v.u + 0x7FFFu + ((v.u >> 16) & 1u);   // RNE
  return (unsigned short)(r >> 16);
}
static __device__ __forceinline__ unsigned int pack2(float a, float b) {
  return (unsigned int)f2bf(a) | ((unsigned int)f2bf(b) << 16);
}

// ---- stage-permutation row maps (element-verified; g always = m&3) --------
static __device__ __forceinline__ int shuf_in(int stg, int u, int dd) {
  if (stg == 0) return ((u >> 4) << 6) | (dd << 4) | ((u & 3) << 2) | ((u >> 2) & 3);
  if (stg == 1) return ((u >> 2) << 4) | (dd << 2) | (u & 3);
  return (u << 2) | dd;                       // stg 2
}
static __device__ __forceinline__ int shuf_out(int stg, int u, int dd) {
  if (stg == 0) return (dd << 6) | ((u & 15) << 2) | (u >> 4);
  if (stg == 1) return ((u >> 4) << 6) | (dd << 4) | ((u & 3) << 2) | ((u >> 2) & 3);
  if (stg == 2) return ((u >> 2) << 4) | (dd << 2) | (u & 3);
  return (u << 2) | dd;                       // stg 3
}

// one MFMA stage from the CURRENT state buffer (stride 80 B, conflict-free:
// (20*c15+4*quad)%32 -> 8 lanes per 4-bank group). a1 is real only for
// quad==0; quads 1-3 read their OWN row's slot 0 (finite data written by the
// own wave's previous stage; B=0 annihilates those k-slots exactly) -> no
// cross-wave LDS dependence anywhere in this helper.
static __device__ __forceinline__ void mfma_stage80(
    const unsigned short* stc, const unsigned short* __restrict__ Bf,
    int w, int lane, int c15, int quad, f32x4 acc[4][3]) {
  short8 bfr[3][2];
  #pragma unroll
  for (int nt = 0; nt < 3; ++nt) {
    bfr[nt][0] = *(const short8*)&Bf[(nt * 2 + 0) * 512 + lane * 8];
    bfr[nt][1] = *(const short8*)&Bf[(nt * 2 + 1) * 512 + lane * 8];
  }
  #pragma unroll
  for (int rt = 0; rt < 4; ++rt) {
    const int rowA = w * 64 + rt * 16 + c15;
    const short8 a0 = *(const short8*)((const char*)stc + rowA * 80 + quad * 16);
    const int a1off = rowA * 80 + ((quad == 0) ? 64 : 0);
    const short8 a1 = *(const short8*)((const char*)stc + a1off);
    #pragma unroll
    for (int nt = 0; nt < 3; ++nt) {
      f32x4 a = {0.f, 0.f, 0.f, 0.f};
      a = __builtin_amdgcn_mfma_f32_16x16x32_bf16(a0, bfr[nt][0], a, 0, 0, 0);
      a = __builtin_amdgcn_mfma_f32_16x16x32_bf16(a1, bfr[nt][1], a, 0, 0, 0);
      acc[rt][nt] = a;
    }
  }
}

// D -> DESTINATION buffer: per (rt,nt) one b64 at the permuted row
template <int STG, bool INPUT>
static __device__ __forceinline__ void stage_writes80(
    unsigned short* dst, const f32x4 acc[4][3], int w, int quad,
    const int* ddv, const int* sv) {
  #pragma unroll
  for (int rt = 0; rt < 4; ++rt) {
    const int u = w * 16 + rt * 4 + quad;
    #pragma unroll
    for (int nt = 0; nt < 3; ++nt) {
      if (sv[nt] < 10) {
        const int dd = ddv[nt];
        const int row = INPUT ? shuf_in(STG, u, dd) : shuf_out(STG, u, dd);
        uint2 v;
        v.x = pack2(acc[rt][nt][0], acc[rt][nt][1]);
        v.y = pack2(acc[rt][nt][2], acc[rt][nt][3]);
        *(uint2*)((char*)dst + row * 80 + sv[nt] * 8) = v;
      }
    }
  }
}

// ---------------- K0: prep (unchanged) --------------------------------------
__global__ __launch_bounds__(256) void k0_prep(
    const float* __restrict__ ic, const float* __restrict__ oc,
    const float* __restrict__ cc, unsigned short* __restrict__ Bt,
    float* __restrict__ c2x, unsigned short* __restrict__ bf1,
    unsigned short* __restrict__ bf3, unsigned short* __restrict__ bf3l) {
  const int t = threadIdx.x;
  const int bx = blockIdx.x;
  if (bx < 1024) {
    const int dly = bx;
    const int D = (dly & 3) * 256 + ((dly >> 2) & 3) * 64 + (dly >> 4);
    const int uC = (t >> 2) * 16 + (t & 3);   // C for c''=4t+j is uC + j*4
    ushort4 pk;
    pk.x = f2bf(cc[(size_t)(uC + 0) * 1024 + D]);
    pk.y = f2bf(cc[(size_t)(uC + 4) * 1024 + D]);
    pk.z = f2bf(cc[(size_t)(uC + 8) * 1024 + D]);
    pk.w = f2bf(cc[(size_t)(uC + 12) * 1024 + D]);
    *(ushort4*)&Bt[(size_t)dly * 1024 + 4 * t] = pk;
  } else if (bx == 1024) {
    for (int idx = t; idx < 1600; idx += 256) {        // c2x[L][w][pi][s]
      int L = idx / 160, rem = idx - L * 160;
      int w = rem / 40, r2 = rem - w * 40;
      int pi = r2 / 10, s = r2 - pi * 10;
      int p1 = pi >> 1, p2 = pi & 1, c1 = w >> 1, c2v = w & 1;
      float a = 0.f;
      for (int r1 = 0; r1 < 10; ++r1)
        a += ic[L * 40 + p1 * 20 + c1 * 10 + r1] *
             ic[400 + r1 * 40 + p2 * 20 + c2v * 10 + s];
      c2x[idx] = a;
    }
  } else if (bx == 1025) {
    for (int idx = t; idx < 12288; idx += 256) {       // bf1
      int j = idx & 7, lane = (idx >> 3) & 63, kc = (idx >> 9) & 1;
      int g2 = idx >> 10, stg = g2 / 3, nt = g2 - stg * 3;
      int c15 = lane & 15, quad = lane >> 4;
      int n = nt * 16 + c15, dd = n / 12, s = n - dd * 12;
      int k = kc * 32 + quad * 8 + j, c = k >> 2, pi = k & 3;
      float v = 0.f;
      if (k < 40 && s < 10) {
        int p1 = pi >> 1, p2 = pi & 1, d1 = dd >> 1, d2 = dd & 1;
        const float* A = ic + (2 * stg + 2) * 400;
        const float* B = ic + (2 * stg + 3) * 400;
        for (int tt = 0; tt < 10; ++tt)
          v += A[c * 40 + p1 * 20 + d1 * 10 + tt] *
               B[tt * 40 + p2 * 20 + d2 * 10 + s];
      }
      bf1[idx] = f2bf(v);
    }
  } else if (bx == 1026) {
    for (int idx = t; idx < 12288; idx += 256) {       // bf3
      int j = idx & 7, lane = (idx >> 3) & 63, kc = (idx >> 9) & 1;
      int g2 = idx >> 10, stg = g2 / 3, nt = g2 - stg * 3;
      int c15 = lane & 15, quad = lane >> 4;
      int n = nt * 16 + c15, dd = n / 12, s = n - dd * 12;
      int k = kc * 32 + quad * 8 + j, c = k >> 2, pi = k & 3;
      float v = 0.f;
      if (k < 40 && s < 10) {
        int d1 = pi >> 1, d2 = pi & 1, p1 = dd >> 1, p2 = dd & 1;
        const float* A = oc + (2 * stg) * 400;
        const float* B = oc + (2 * stg + 1) * 400;
        for (int tt = 0; tt < 10; ++tt)
          v += A[c * 40 + p1 * 20 + d1 * 10 + tt] *
               B[tt * 40 + p2 * 20 + d2 * 10 + s];
      }
      bf3[idx] = f2bf(v);
    }
  } else {
    for (int idx = t; idx < 10240; idx += 256) {       // bf3l (trace folded)
      int j = idx & 7, lane = (idx >> 3) & 63, kc = (idx >> 9) & 1, L = idx >> 10;
      int c15 = lane & 15, quad = lane >> 4;
      int k = kc * 32 + quad * 8 + j, c = k >> 2, pi = k & 3;
      float v = 0.f;
      if (k < 40 && c15 < 4) {
        int dd = c15, d1 = pi >> 1, d2 = pi & 1, p1 = dd >> 1, p2 = dd & 1;
        for (int tt = 0; tt < 10; ++tt)
          v += oc[8 * 400 + c * 40 + p1 * 20 + d1 * 10 + tt] *
               oc[9 * 400 + tt * 40 + p2 * 20 + d2 * 10 + L];
      }
      bf3l[idx] = f2bf(v);
    }
  }
}

// ---------------- K1: input sweep (R17: barrier-free, direct S stores) -----
__global__ __launch_bounds__(256, 4) void k1_insweep(
    const float* __restrict__ x, const float* __restrict__ c2x,
    const unsigned short* __restrict__ bf1, unsigned short* __restrict__ S) {
  __shared__ __align__(16) unsigned short st[20480];   // 2 x 10240 shorts
  const int t = threadIdx.x, bx = blockIdx.x;
  const int b = bx / 10, L = bx - b * 10;
  const int lane = t & 63, w = t >> 6;
  const int c15 = lane & 15, quad = lane >> 4;
  int ddv[3], sv[3];
  #pragma unroll
  for (int nt = 0; nt < 3; ++nt) {
    int n = nt * 16 + c15; ddv[nt] = n / 12; sv[nt] = n - ddv[nt] * 12;
  }
  unsigned short* bufA = st;
  unsigned short* bufB = st + 10240;
  // ---- stage X: absorb x bits p1..p4 via fused cores (0,1), K=4 -> bufA ---
  {
    const float* xb = x + (size_t)b * 1024;
    const float* C2 = c2x + L * 160 + w * 40;
    float accx[4][10];
    #pragma unroll
    for (int g = 0; g < 4; ++g)
      #pragma unroll
      for (int s = 0; s < 10; ++s) accx[g][s] = 0.f;
    #pragma unroll
    for (int pi = 0; pi < 4; ++pi) {
      float xv[4];
      #pragma unroll
      for (int g = 0; g < 4; ++g) xv[g] = xb[pi * 256 + g * 64 + lane];
      #pragma unroll
      for (int s = 0; s < 10; ++s) {
        const float bv = C2[pi * 10 + s];
        #pragma unroll
        for (int g = 0; g < 4; ++g) accx[g][s] = fmaf(xv[g], bv, accx[g][s]);
      }
    }
    const int row = w * 64 + c15 * 4 + quad;   // own-slice rows only
    #pragma unroll
    for (int s = 0; s < 10; ++s) {
      uint2 v;
      v.x = pack2(accx[0][s], accx[1][s]);
      v.y = pack2(accx[2][s], accx[3][s]);
      *(uint2*)((char*)bufA + row * 80 + s * 8) = v;
    }
  }
  f32x4 acc[4][3];
  // stage 0: A -> B   (own-slice; in-wave DS order suffices)
  mfma_stage80(bufA, bf1 + 0 * 3072, w, lane, c15, quad, acc);
  stage_writes80<0, true>(bufB, acc, w, quad, ddv, sv);
  // stage 1: B -> A
  mfma_stage80(bufB, bf1 + 1 * 3072, w, lane, c15, quad, acc);
  stage_writes80<1, true>(bufA, acc, w, quad, ddv, sv);
  // stage 2: A -> B
  mfma_stage80(bufA, bf1 + 2 * 3072, w, lane, c15, quad, acc);
  stage_writes80<2, true>(bufB, acc, w, quad, ddv, sv);
  // stage 3: B -> S (global), col c'' = u*16 + dd*4 + i  (i = c7c8)
  mfma_stage80(bufB, bf1 + 3 * 3072, w, lane, c15, quad, acc);
  #pragma unroll
  for (int rt = 0; rt < 4; ++rt) {
    const int u = w * 16 + rt * 4 + quad;
    #pragma unroll
    for (int nt = 0; nt < 3; ++nt) {
      if (sv[nt] < 10) {
        uint2 v;
        v.x = pack2(acc[rt][nt][0], acc[rt][nt][1]);
        v.y = pack2(acc[rt][nt][2], acc[rt][nt][3]);
        *(uint2*)&S[((size_t)(bx * 10 + sv[nt])) * 1024 + u * 16 + ddv[nt] * 4] = v;
      }
    }
  }
}

// ---------------- K2: MFMA GEMM (R22: 256x128, 2-slot 48 KB, 3 blocks/CU) --
// C[m][n] = sum_k A[m][k]*B[n][k];  A = Bt [1024][1024], B = S [51200][1024].
// 256 thr = 4 waves (2M x 2N); per-wave 128x64 output -> acc[8][4].
// LDS 48 KiB = 2 slots x 24 KiB; slot = [A 256 rows | B 128 rows] x
// 32 bf16 (64 B/row), 16B-slot col swizzled by (row>>1)&3.
// Phase p (p=0..31, K=32 each): read slot p%2; stage region p+1 into slot
// (p+1)%2 (last read in phase p-1, sealed by that barrier); 32 MFMA;
// vmcnt(0) (own 6 loads issued at phase start, ~1400+ cyc earlier — HBM
// ~900 cyc covered); s_barrier. 3 resident blocks/CU fill residual stalls.

#define K2_STAGE6(SLOT)                                                        \
  {                                                                            \
    char* lb = ldsb + (SLOT) * 24576 + w * 6144;                               \
    _Pragma("unroll")                                                          \
    for (int i = 0; i < 6; ++i) {                                              \
      __builtin_amdgcn_global_load_lds(                                        \
          (const __attribute__((address_space(1))) void*)(gsrc[i]),            \
          (__attribute__((address_space(3))) void*)(lb + (i << 10)), 16, 0, 0);\
      gsrc[i] += 32;                         /* advance one region (64 B) */   \
    }                                                                          \
  }

#define K2_PHASE(RSLOT, SSLOT, DO_STAGE, VMCNT_ASM, DO_SYNC)                   \
  {                                                                            \
    const char* rb = ldsb + (RSLOT) * 24576;                                   \
    short8 afr[8], bfr[4];                                                     \
    _Pragma("unroll")                                                          \
    for (int mt = 0; mt < 8; ++mt)                                             \
      afr[mt] = *(const short8*)(rb + ((arow0 + (mt << 4)) << 6) + aswz);      \
    _Pragma("unroll")                                                          \
    for (int nt = 0; nt < 4; ++nt)                                             \
      bfr[nt] = *(const short8*)(rb + 16384 + ((brow0 + (nt << 4)) << 6) + aswz);\
    if (DO_STAGE) K2_STAGE6(SSLOT)                                             \
    __builtin_amdgcn_s_setprio(1);                                             \
    _Pragma("unroll")                                                          \
    for (int mt = 0; mt < 8; ++mt)                                             \
      _Pragma("unroll")                                                        \
      for (int nt = 0; nt < 4; ++nt)                                           \
        acc[mt][nt] = __builtin_amdgcn_mfma_f32_16x16x32_bf16(                 \
            afr[mt], bfr[nt], acc[mt][nt], 0, 0, 0);                           \
    __builtin_amdgcn_s_setprio(0);                                             \
    if (DO_SYNC) {                                                             \
      VMCNT_ASM;                            /* own region-(p+1) loads done */  \
      __builtin_amdgcn_s_barrier();         /* -> done for all waves */        \
      __builtin_amdgcn_sched_barrier(0);                                       \
    }                                                                          \
  }

#define K2_VM0 asm volatile("s_waitcnt vmcnt(0)" ::: "memory")

__global__ __launch_bounds__(256, 2) void k2_gemm(
    const unsigned short* __restrict__ A,   // Bt [1024][1024]
    const unsigned short* __restrict__ B,   // S  [51200][1024]
    unsigned short* __restrict__ U2a,       // [5120][256][32] bf16
    unsigned short* __restrict__ U2b) {     // [5120][256][8]  bf16
  __shared__ __align__(16) char ldsb[49152];    // 2 slots x 24576 B
  const int tid = threadIdx.x, bx = blockIdx.x;
  // T1: bijective XCD swizzle (1600 % 8 == 0). 4 consecutive bids share one
  // bn-panel of B (bm 0..3) -> L2 reuse of the streamed operand.
  const int bid = (bx & 7) * 200 + (bx >> 3);
  const int bm = bid & 3, bn = bid >> 2;          // 4 M-tiles x 400 N-tiles
  const int Mtile0 = bm << 8, Ntile0 = bn << 7;
  const int w = tid >> 6, lane = tid & 63;
  const int c15 = lane & 15, quad = lane >> 4;
  const int wm = w >> 1, wn = w & 1;              // 2 x 2 wave grid

  // ds_read addressing (lane-constant swizzle: (row>>1)&3 == (c15>>1)&3
  // for both the A section and the B section at +16384)
  const int arow0 = (wm << 7) + c15;
  const int brow0 = (wn << 6) + c15;
  const int aswz = ((quad ^ ((c15 >> 1) & 3)) << 4);

  // staging: wave w stages slot rows [w*96, w*96+96) = 6 chunks of 16 rows.
  // chunk rows < 256 -> A section (global row Mtile0+row); else B section
  // (global row Ntile0+row-256). per-lane source col pre-swizzled:
  // logical 16B slot = (lane&3) ^ ((row>>1)&3) = (lane&3) ^ ((lane>>3)&3).
  const unsigned short* gsrc[6];
  #pragma unroll
  for (int i = 0; i < 6; ++i) {
    const int rowc = w * 96 + i * 16;             // chunk base row in slot
    const int row = rowc + (lane >> 2);
    const unsigned short* g = (rowc < 256)
        ? (A + ((size_t)(Mtile0 + row) << 10))
        : (B + ((size_t)(Ntile0 + row - 256) << 10));
    gsrc[i] = g + (((lane & 3) ^ ((lane >> 3) & 3)) << 3);
  }

  f32x4 acc[8][4];
  #pragma unroll
  for (int i = 0; i < 8; ++i)
    #pragma unroll
    for (int j = 0; j < 4; ++j) acc[i][j] = (f32x4){0.f, 0.f, 0.f, 0.f};

  // prologue: stage region 0 -> slot 0; wait; barrier
  K2_STAGE6(0)
  K2_VM0;
  __builtin_amdgcn_s_barrier();
  __builtin_amdgcn_sched_barrier(0);

  // phases 0..29: read slot p%2, stage region p+1 -> slot (p+1)%2
  #pragma unroll 1
  for (int it = 0; it < 15; ++it) {
    K2_PHASE(0, 1, true, K2_VM0, true)
    K2_PHASE(1, 0, true, K2_VM0, true)
  }
  // phase 30: read slot 0, stage region 31 -> slot 1
  K2_PHASE(0, 1, true, K2_VM0, true)
  // phase 31: read slot 1, last compute, no sync needed before epilogue
  K2_PHASE(1, 0, false, (void)0, false)

  // epilogue: D rows = delta (i = d1d2), cols = S rows (bl, r)
  const int col0 = Ntile0 + (wn << 6) + c15;
  const int rowb = Mtile0 + (wm << 7);
  #pragma unroll
  for (int nt = 0; nt < 4; ++nt) {
    const int n = col0 + (nt << 4);
    const int bl = n / 10;
    const int r = n - bl * 10;
    char* dst = (r < 8)
        ? (char*)U2a + (size_t)bl * 16384 + (size_t)r * 8
        : (char*)U2b + (size_t)bl * 4096 + (size_t)(r - 8) * 8;
    const int rbs = (r < 8) ? 64 : 16;
    #pragma unroll
    for (int mt = 0; mt < 8; ++mt) {
      const int mp = (rowb + (mt << 4) + (quad << 2)) >> 2;   // delta>>2
      uint2 v;
      v.x = pack2(acc[mt][nt][0], acc[mt][nt][1]);
      v.y = pack2(acc[mt][nt][2], acc[mt][nt][3]);
      *(uint2*)(dst + (size_t)mp * rbs) = v;
    }
  }
}

// ---------------- K3: output sweep (R21: in-place 20 KB, plain stores) -----
// Single buffer: stage 0 writes cross wave slices (one barrier); stages 1-4
// read+write only the wave's own 64-row slice IN PLACE (reads issue before
// writes; same-wave DS ordering). Epilogue: plain f32 partial stores — each
// oidx written exactly once per block (u=0..63 x i,c15 covers 1024).
__global__ __launch_bounds__(256, 4) void k3_outsweep(
    const unsigned short* __restrict__ U2a, const unsigned short* __restrict__ U2b,
    const unsigned short* __restrict__ bf3, const unsigned short* __restrict__ bf3l,
    float* __restrict__ Up) {              // [5120][1024] f32 partials
  __shared__ __align__(16) unsigned short st[10240];   // 20480 B in-place
  const int t = threadIdx.x, bx = blockIdx.x;
  const int L = bx - (bx / 10) * 10;
  const int lane = t & 63, w = t >> 6;
  const int c15 = lane & 15, quad = lane >> 4;
  int ddv[3], sv[3];
  #pragma unroll
  for (int nt = 0; nt < 3; ++nt) {
    int n = nt * 16 + c15; ddv[nt] = n / 12; sv[nt] = n - ddv[nt] * 12;
  }
  f32x4 acc[4][3];
  // ---- stage 0: A-frags from global U2 (coalesced), cores (0,1) -> st ----
  {
    short8 bfr[3][2];
    #pragma unroll
    for (int nt = 0; nt < 3; ++nt) {
      bfr[nt][0] = *(const short8*)&bf3[(nt * 2 + 0) * 512 + lane * 8];
      bfr[nt][1] = *(const short8*)&bf3[(nt * 2 + 1) * 512 + lane * 8];
    }
    const char* Ua = (const char*)U2a + (size_t)bx * 16384;
    const char* Ub = (const char*)U2b + (size_t)bx * 4096;
    #pragma unroll
    for (int rt = 0; rt < 4; ++rt) {
      const int m = w * 64 + rt * 16 + c15;
      const short8 a0 = *(const short8*)(Ua + m * 64 + quad * 16);
      const short8 a1 = *(const short8*)(Ub + m * 16);   // quads 1-3: k>=40, B=0
      #pragma unroll
      for (int nt = 0; nt < 3; ++nt) {
        f32x4 a = {0.f, 0.f, 0.f, 0.f};
        a = __builtin_amdgcn_mfma_f32_16x16x32_bf16(a0, bfr[nt][0], a, 0, 0, 0);
        a = __builtin_amdgcn_mfma_f32_16x16x32_bf16(a1, bfr[nt][1], a, 0, 0, 0);
        acc[rt][nt] = a;
      }
    }
    stage_writes80<0, false>(st, acc, w, quad, ddv, sv);
  }
  __syncthreads();   // stage 0 writes cross wave slices — the ONE barrier
  // stage 1: in-place (own-slice reads fully issued before own-slice writes)
  mfma_stage80(st, bf3 + 1 * 3072, w, lane, c15, quad, acc);
  stage_writes80<1, false>(st, acc, w, quad, ddv, sv);
  // stage 2: in-place
  mfma_stage80(st, bf3 + 2 * 3072, w, lane, c15, quad, acc);
  stage_writes80<2, false>(st, acc, w, quad, ddv, sv);
  // stage 3: in-place
  mfma_stage80(st, bf3 + 3 * 3072, w, lane, c15, quad, acc);
  stage_writes80<3, false>(st, acc, w, quad, ddv, sv);
  // ---- stage 4: cores (8,9) + ring trace from st -> Up[bx] ---------------
  {
    const unsigned short* Bf = bf3l + L * 1024;
    const short8 b0 = *(const short8*)&Bf[lane * 8];
    const short8 b1 = *(const short8*)&Bf[512 + lane * 8];
    #pragma unroll
    for (int rt = 0; rt < 4; ++rt) {
      const int rowA = w * 64 + rt * 16 + c15;
      const short8 a0 = *(const short8*)((const char*)st + rowA * 80 + quad * 16);
      const int a1off = rowA * 80 + ((quad == 0) ? 64 : 0);
      const short8 a1 = *(const short8*)((const char*)st + a1off);
      f32x4 a = {0.f, 0.f, 0.f, 0.f};
      a = __builtin_amdgcn_mfma_f32_16x16x32_bf16(a0, b0, a, 0, 0, 0);
      a = __builtin_amdgcn_mfma_f32_16x16x32_bf16(a1, b1, a, 0, 0, 0);
      if (c15 < 4) {
        const int u = w * 16 + rt * 4 + quad;
        #pragma unroll
        for (int i = 0; i < 4; ++i) {
          const int oidx = u * 16 + i * 4 + c15;   // p'1..p'10
          Up[((size_t)bx << 10) + oidx] = a[i];
        }
      }
    }
  }
}

// ---------------- K4: f64 reduce of 10 L-partials + bias -> out -------------
// f64 accumulation: ulp(1e13) ~ 2e-3 -> exact sum of partials, no ordering
// jitter, no systematic rounding. Deterministic across graph replays.
__global__ __launch_bounds__(256) void k4_reduce(
    const float* __restrict__ Up, const float* __restrict__ bias,
    float* __restrict__ out) {
  const int idx = blockIdx.x * 256 + threadIdx.x;   // 0..524287
  const int o = idx & 1023;
  const int b = idx >> 10;
  const float* p = Up + ((size_t)(b * 10) << 10) + o;
  double s = 0.0;
  #pragma unroll
  for (int L = 0; L < 10; ++L) s += (double)p[(size_t)L << 10];
  s += (double)bias[o];
  out[idx] = (float)s;
}

// ---------------- launch ----------------------------------------------------
extern "C" void kernel_launch(void* const* d_in, const int* in_sizes, int n_in,
                              void* d_out, int out_size, void* d_ws, size_t ws_size,
                              hipStream_t stream) {
  (void)in_sizes; (void)n_in; (void)ws_size; (void)out_size;
  const float* x    = (const float*)d_in[0];
  const float* ic   = (const float*)d_in[1];
  const float* oc   = (const float*)d_in[2];
  const float* cc   = (const float*)d_in[3];
  const float* bias = (const float*)d_in[4];
  float* out = (float*)d_out;

  char* ws = (char*)d_ws;
  unsigned short* S    = (unsigned short*)(ws);              // 104857600 B
  unsigned short* U2a  = (unsigned short*)(ws + 104857600);  //  83886080 B
  unsigned short* U2b  = (unsigned short*)(ws + 188743680);  //  20971520 B
  unsigned short* Bt   = (unsigned short*)(ws + 209715200);  //   2097152 B
  float*          c2x  = (float*)(ws + 211812352);           //      6400 B
  unsigned short* bf1  = (unsigned short*)(ws + 211818752);  //     24576 B
  unsigned short* bf3  = (unsigned short*)(ws + 211843328);  //     24576 B
  unsigned short* bf3l = (unsigned short*)(ws + 211867904);  //     20480 B
  // Up reuses the S region (S fully consumed by k2 before k3 runs):
  float*          Up   = (float*)(ws);                       //  20971520 B

  k0_prep<<<1028, 256, 0, stream>>>(ic, oc, cc, Bt, c2x, bf1, bf3, bf3l);
  k1_insweep<<<5120, 256, 0, stream>>>(x, c2x, bf1, S);
  k2_gemm<<<1600, 256, 0, stream>>>(Bt, S, U2a, U2b);
  k3_outsweep<<<5120, 256, 0, stream>>>(U2a, U2b, bf3, bf3l, Up);
  k4_reduce<<<2048, 256, 0, stream>>>(Up, bias, out);
}

// Round 14
// 306.623 us; speedup vs baseline: 1.0726x; 1.0726x over previous
//
#include <hip/hip_runtime.h>
#include <cstdint>
#include <cstddef>

// ---------------------------------------------------------------------------
// TWLayer — all-MFMA pipeline.  R24 = exact restore of R21 (307.6 us, PASSED,
// deterministic absmax 1.887e7) after R23's k1-in-place falsification.
//   K1:  R17 double-buffered (barrier-free own-slice stages, direct S
//        stores). IN-PLACE BANNED for k1: R23 measured a deterministic
//        output change (absmax 1.887e7 -> 2.94e7) despite a source-level
//        read-before-write/full-coverage audit — empirical bit-exactness
//        is the only accepted proof for in-place LDS staging.
//   K2:  R12 exact (118.3 us plateau; 5 failed variants around it, frozen).
//   K3:  R21 in-place 20 KB + plain partial stores (validated by R21's
//        measured pass).
//   K4:  f64 reduce of 10 L-partials + bias — deterministic; numerics
//        FROZEN (atomics re-rolled ordering per graph replay, R20 fail).
// ---------------------------------------------------------------------------

typedef __attribute__((ext_vector_type(8))) short short8;   // 8 x bf16
typedef __attribute__((ext_vector_type(4))) float f32x4;

static __device__ __forceinline__ unsigned short f2bf(float f) {
  union { float f; unsigned int u; } v; v.f = f;
  unsigned int r = v.u + 0x7FFFu + ((v.u >> 16) & 1u);   // RNE
  return (unsigned short)(r >> 16);
}
static __device__ __forceinline__ unsigned int pack2(float a, float b) {
  return (unsigned int)f2bf(a) | ((unsigned int)f2bf(b) << 16);
}

// ---- stage-permutation row maps (element-verified; g always = m&3) --------
static __device__ __forceinline__ int shuf_in(int stg, int u, int dd) {
  if (stg == 0) return ((u >> 4) << 6) | (dd << 4) | ((u & 3) << 2) | ((u >> 2) & 3);
  if (stg == 1) return ((u >> 2) << 4) | (dd << 2) | (u & 3);
  return (u << 2) | dd;                       // stg 2
}
static __device__ __forceinline__ int shuf_out(int stg, int u, int dd) {
  if (stg == 0) return (dd << 6) | ((u & 15) << 2) | (u >> 4);
  if (stg == 1) return ((u >> 4) << 6) | (dd << 4) | ((u & 3) << 2) | ((u >> 2) & 3);
  if (stg == 2) return ((u >> 2) << 4) | (dd << 2) | (u & 3);
  return (u << 2) | dd;                       // stg 3
}

// one MFMA stage from the CURRENT state buffer (stride 80 B, conflict-free:
// (20*c15+4*quad)%32 -> 8 lanes per 4-bank group). a1 is real only for
// quad==0; quads 1-3 read their OWN row's slot 0 (finite data written by the
// own wave's previous stage; B=0 annihilates those k-slots exactly) -> no
// cross-wave LDS dependence anywhere in this helper.
static __device__ __forceinline__ void mfma_stage80(
    const unsigned short* stc, const unsigned short* __restrict__ Bf,
    int w, int lane, int c15, int quad, f32x4 acc[4][3]) {
  short8 bfr[3][2];
  #pragma unroll
  for (int nt = 0; nt < 3; ++nt) {
    bfr[nt][0] = *(const short8*)&Bf[(nt * 2 + 0) * 512 + lane * 8];
    bfr[nt][1] = *(const short8*)&Bf[(nt * 2 + 1) * 512 + lane * 8];
  }
  #pragma unroll
  for (int rt = 0; rt < 4; ++rt) {
    const int rowA = w * 64 + rt * 16 + c15;
    const short8 a0 = *(const short8*)((const char*)stc + rowA * 80 + quad * 16);
    const int a1off = rowA * 80 + ((quad == 0) ? 64 : 0);
    const short8 a1 = *(const short8*)((const char*)stc + a1off);
    #pragma unroll
    for (int nt = 0; nt < 3; ++nt) {
      f32x4 a = {0.f, 0.f, 0.f, 0.f};
      a = __builtin_amdgcn_mfma_f32_16x16x32_bf16(a0, bfr[nt][0], a, 0, 0, 0);
      a = __builtin_amdgcn_mfma_f32_16x16x32_bf16(a1, bfr[nt][1], a, 0, 0, 0);
      acc[rt][nt] = a;
    }
  }
}

// D -> DESTINATION buffer: per (rt,nt) one b64 at the permuted row
template <int STG, bool INPUT>
static __device__ __forceinline__ void stage_writes80(
    unsigned short* dst, const f32x4 acc[4][3], int w, int quad,
    const int* ddv, const int* sv) {
  #pragma unroll
  for (int rt = 0; rt < 4; ++rt) {
    const int u = w * 16 + rt * 4 + quad;
    #pragma unroll
    for (int nt = 0; nt < 3; ++nt) {
      if (sv[nt] < 10) {
        const int dd = ddv[nt];
        const int row = INPUT ? shuf_in(STG, u, dd) : shuf_out(STG, u, dd);
        uint2 v;
        v.x = pack2(acc[rt][nt][0], acc[rt][nt][1]);
        v.y = pack2(acc[rt][nt][2], acc[rt][nt][3]);
        *(uint2*)((char*)dst + row * 80 + sv[nt] * 8) = v;
      }
    }
  }
}

// ---------------- K0: prep (unchanged) --------------------------------------
__global__ __launch_bounds__(256) void k0_prep(
    const float* __restrict__ ic, const float* __restrict__ oc,
    const float* __restrict__ cc, unsigned short* __restrict__ Bt,
    float* __restrict__ c2x, unsigned short* __restrict__ bf1,
    unsigned short* __restrict__ bf3, unsigned short* __restrict__ bf3l) {
  const int t = threadIdx.x;
  const int bx = blockIdx.x;
  if (bx < 1024) {
    const int dly = bx;
    const int D = (dly & 3) * 256 + ((dly >> 2) & 3) * 64 + (dly >> 4);
    const int uC = (t >> 2) * 16 + (t & 3);   // C for c''=4t+j is uC + j*4
    ushort4 pk;
    pk.x = f2bf(cc[(size_t)(uC + 0) * 1024 + D]);
    pk.y = f2bf(cc[(size_t)(uC + 4) * 1024 + D]);
    pk.z = f2bf(cc[(size_t)(uC + 8) * 1024 + D]);
    pk.w = f2bf(cc[(size_t)(uC + 12) * 1024 + D]);
    *(ushort4*)&Bt[(size_t)dly * 1024 + 4 * t] = pk;
  } else if (bx == 1024) {
    for (int idx = t; idx < 1600; idx += 256) {        // c2x[L][w][pi][s]
      int L = idx / 160, rem = idx - L * 160;
      int w = rem / 40, r2 = rem - w * 40;
      int pi = r2 / 10, s = r2 - pi * 10;
      int p1 = pi >> 1, p2 = pi & 1, c1 = w >> 1, c2v = w & 1;
      float a = 0.f;
      for (int r1 = 0; r1 < 10; ++r1)
        a += ic[L * 40 + p1 * 20 + c1 * 10 + r1] *
             ic[400 + r1 * 40 + p2 * 20 + c2v * 10 + s];
      c2x[idx] = a;
    }
  } else if (bx == 1025) {
    for (int idx = t; idx < 12288; idx += 256) {       // bf1
      int j = idx & 7, lane = (idx >> 3) & 63, kc = (idx >> 9) & 1;
      int g2 = idx >> 10, stg = g2 / 3, nt = g2 - stg * 3;
      int c15 = lane & 15, quad = lane >> 4;
      int n = nt * 16 + c15, dd = n / 12, s = n - dd * 12;
      int k = kc * 32 + quad * 8 + j, c = k >> 2, pi = k & 3;
      float v = 0.f;
      if (k < 40 && s < 10) {
        int p1 = pi >> 1, p2 = pi & 1, d1 = dd >> 1, d2 = dd & 1;
        const float* A = ic + (2 * stg + 2) * 400;
        const float* B = ic + (2 * stg + 3) * 400;
        for (int tt = 0; tt < 10; ++tt)
          v += A[c * 40 + p1 * 20 + d1 * 10 + tt] *
               B[tt * 40 + p2 * 20 + d2 * 10 + s];
      }
      bf1[idx] = f2bf(v);
    }
  } else if (bx == 1026) {
    for (int idx = t; idx < 12288; idx += 256) {       // bf3
      int j = idx & 7, lane = (idx >> 3) & 63, kc = (idx >> 9) & 1;
      int g2 = idx >> 10, stg = g2 / 3, nt = g2 - stg * 3;
      int c15 = lane & 15, quad = lane >> 4;
      int n = nt * 16 + c15, dd = n / 12, s = n - dd * 12;
      int k = kc * 32 + quad * 8 + j, c = k >> 2, pi = k & 3;
      float v = 0.f;
      if (k < 40 && s < 10) {
        int d1 = pi >> 1, d2 = pi & 1, p1 = dd >> 1, p2 = dd & 1;
        const float* A = oc + (2 * stg) * 400;
        const float* B = oc + (2 * stg + 1) * 400;
        for (int tt = 0; tt < 10; ++tt)
          v += A[c * 40 + p1 * 20 + d1 * 10 + tt] *
               B[tt * 40 + p2 * 20 + d2 * 10 + s];
      }
      bf3[idx] = f2bf(v);
    }
  } else {
    for (int idx = t; idx < 10240; idx += 256) {       // bf3l (trace folded)
      int j = idx & 7, lane = (idx >> 3) & 63, kc = (idx >> 9) & 1, L = idx >> 10;
      int c15 = lane & 15, quad = lane >> 4;
      int k = kc * 32 + quad * 8 + j, c = k >> 2, pi = k & 3;
      float v = 0.f;
      if (k < 40 && c15 < 4) {
        int dd = c15, d1 = pi >> 1, d2 = pi & 1, p1 = dd >> 1, p2 = dd & 1;
        for (int tt = 0; tt < 10; ++tt)
          v += oc[8 * 400 + c * 40 + p1 * 20 + d1 * 10 + tt] *
               oc[9 * 400 + tt * 40 + p2 * 20 + d2 * 10 + L];
      }
      bf3l[idx] = f2bf(v);
    }
  }
}

// ---------------- K1: input sweep (R17: barrier-free, double-buffered) -----
__global__ __launch_bounds__(256, 4) void k1_insweep(
    const float* __restrict__ x, const float* __restrict__ c2x,
    const unsigned short* __restrict__ bf1, unsigned short* __restrict__ S) {
  __shared__ __align__(16) unsigned short st[20480];   // 2 x 10240 shorts
  const int t = threadIdx.x, bx = blockIdx.x;
  const int b = bx / 10, L = bx - b * 10;
  const int lane = t & 63, w = t >> 6;
  const int c15 = lane & 15, quad = lane >> 4;
  int ddv[3], sv[3];
  #pragma unroll
  for (int nt = 0; nt < 3; ++nt) {
    int n = nt * 16 + c15; ddv[nt] = n / 12; sv[nt] = n - ddv[nt] * 12;
  }
  unsigned short* bufA = st;
  unsigned short* bufB = st + 10240;
  // ---- stage X: absorb x bits p1..p4 via fused cores (0,1), K=4 -> bufA ---
  {
    const float* xb = x + (size_t)b * 1024;
    const float* C2 = c2x + L * 160 + w * 40;
    float accx[4][10];
    #pragma unroll
    for (int g = 0; g < 4; ++g)
      #pragma unroll
      for (int s = 0; s < 10; ++s) accx[g][s] = 0.f;
    #pragma unroll
    for (int pi = 0; pi < 4; ++pi) {
      float xv[4];
      #pragma unroll
      for (int g = 0; g < 4; ++g) xv[g] = xb[pi * 256 + g * 64 + lane];
      #pragma unroll
      for (int s = 0; s < 10; ++s) {
        const float bv = C2[pi * 10 + s];
        #pragma unroll
        for (int g = 0; g < 4; ++g) accx[g][s] = fmaf(xv[g], bv, accx[g][s]);
      }
    }
    const int row = w * 64 + c15 * 4 + quad;   // own-slice rows only
    #pragma unroll
    for (int s = 0; s < 10; ++s) {
      uint2 v;
      v.x = pack2(accx[0][s], accx[1][s]);
      v.y = pack2(accx[2][s], accx[3][s]);
      *(uint2*)((char*)bufA + row * 80 + s * 8) = v;
    }
  }
  f32x4 acc[4][3];
  // stage 0: A -> B   (own-slice; in-wave DS order suffices)
  mfma_stage80(bufA, bf1 + 0 * 3072, w, lane, c15, quad, acc);
  stage_writes80<0, true>(bufB, acc, w, quad, ddv, sv);
  // stage 1: B -> A
  mfma_stage80(bufB, bf1 + 1 * 3072, w, lane, c15, quad, acc);
  stage_writes80<1, true>(bufA, acc, w, quad, ddv, sv);
  // stage 2: A -> B
  mfma_stage80(bufA, bf1 + 2 * 3072, w, lane, c15, quad, acc);
  stage_writes80<2, true>(bufB, acc, w, quad, ddv, sv);
  // stage 3: B -> S (global), col c'' = u*16 + dd*4 + i  (i = c7c8)
  mfma_stage80(bufB, bf1 + 3 * 3072, w, lane, c15, quad, acc);
  #pragma unroll
  for (int rt = 0; rt < 4; ++rt) {
    const int u = w * 16 + rt * 4 + quad;
    #pragma unroll
    for (int nt = 0; nt < 3; ++nt) {
      if (sv[nt] < 10) {
        uint2 v;
        v.x = pack2(acc[rt][nt][0], acc[rt][nt][1]);
        v.y = pack2(acc[rt][nt][2], acc[rt][nt][3]);
        *(uint2*)&S[((size_t)(bx * 10 + sv[nt])) * 1024 + u * 16 + ddv[nt] * 4] = v;
      }
    }
  }
}

// ---------------- K2: MFMA GEMM (R12 exact: 3-slot 72 KB, vmcnt(6)) --------
// C[m][n] = sum_k A[m][k]*B[n][k];  A = Bt [1024][1024], B = S [51200][1024].
// 256 thr = 4 waves (2M x 2N); per-wave 128x64 output -> acc[8][4].
// LDS 72 KiB = 3 slots x 24 KiB; slot = [A 256 rows | B 128 rows] x
// 32 bf16 (64 B/row), 16B-slot col swizzled by (row>>1)&3.
// Phase p (p=0..31, K=32 each): read slot p%3; stage region p+2 into slot
// (p+2)%3; 32 MFMA; vmcnt(6) -> region p+1 complete; s_barrier.

#define K2_STAGE6(SLOT)                                                        \
  {                                                                            \
    char* lb = ldsb + (SLOT) * 24576 + w * 6144;                               \
    _Pragma("unroll")                                                          \
    for (int i = 0; i < 6; ++i) {                                              \
      __builtin_amdgcn_global_load_lds(                                        \
          (const __attribute__((address_space(1))) void*)(gsrc[i]),            \
          (__attribute__((address_space(3))) void*)(lb + (i << 10)), 16, 0, 0);\
      gsrc[i] += 32;                         /* advance one region (64 B) */   \
    }                                                                          \
  }

#define K2_PHASE(RSLOT, SSLOT, DO_STAGE, VMCNT_ASM, DO_SYNC)                   \
  {                                                                            \
    const char* rb = ldsb + (RSLOT) * 24576;                                   \
    short8 afr[8], bfr[4];                                                     \
    _Pragma("unroll")                                                          \
    for (int mt = 0; mt < 8; ++mt)                                             \
      afr[mt] = *(const short8*)(rb + ((arow0 + (mt << 4)) << 6) + aswz);      \
    _Pragma("unroll")                                                          \
    for (int nt = 0; nt < 4; ++nt)                                             \
      bfr[nt] = *(const short8*)(rb + 16384 + ((brow0 + (nt << 4)) << 6) + aswz);\
    if (DO_STAGE) K2_STAGE6(SSLOT)                                             \
    __builtin_amdgcn_s_setprio(1);                                             \
    _Pragma("unroll")                                                          \
    for (int mt = 0; mt < 8; ++mt)                                             \
      _Pragma("unroll")                                                        \
      for (int nt = 0; nt < 4; ++nt)                                           \
        acc[mt][nt] = __builtin_amdgcn_mfma_f32_16x16x32_bf16(                 \
            afr[mt], bfr[nt], acc[mt][nt], 0, 0, 0);                           \
    __builtin_amdgcn_s_setprio(0);                                             \
    if (DO_SYNC) {                                                             \
      VMCNT_ASM;                            /* region p+1 complete (own) */    \
      __builtin_amdgcn_s_barrier();         /* -> complete for all waves */    \
      __builtin_amdgcn_sched_barrier(0);                                       \
    }                                                                          \
  }

#define K2_VM6 asm volatile("s_waitcnt vmcnt(6)" ::: "memory")
#define K2_VM0 asm volatile("s_waitcnt vmcnt(0)" ::: "memory")

__global__ __launch_bounds__(256, 2) void k2_gemm(
    const unsigned short* __restrict__ A,   // Bt [1024][1024]
    const unsigned short* __restrict__ B,   // S  [51200][1024]
    unsigned short* __restrict__ U2a,       // [5120][256][32] bf16
    unsigned short* __restrict__ U2b) {     // [5120][256][8]  bf16
  __shared__ __align__(16) char ldsb[73728];    // 3 slots x 24576 B
  const int tid = threadIdx.x, bx = blockIdx.x;
  // T1: bijective XCD swizzle (1600 % 8 == 0). 4 consecutive bids share one
  // bn-panel of B (bm 0..3) -> L2 reuse of the streamed operand.
  const int bid = (bx & 7) * 200 + (bx >> 3);
  const int bm = bid & 3, bn = bid >> 2;          // 4 M-tiles x 400 N-tiles
  const int Mtile0 = bm << 8, Ntile0 = bn << 7;
  const int w = tid >> 6, lane = tid & 63;
  const int c15 = lane & 15, quad = lane >> 4;
  const int wm = w >> 1, wn = w & 1;              // 2 x 2 wave grid

  // ds_read addressing (lane-constant swizzle: (row>>1)&3 == (c15>>1)&3
  // for both the A section and the B section at +16384)
  const int arow0 = (wm << 7) + c15;
  const int brow0 = (wn << 6) + c15;
  const int aswz = ((quad ^ ((c15 >> 1) & 3)) << 4);

  // staging: wave w stages slot rows [w*96, w*96+96) = 6 chunks of 16 rows.
  // chunk rows < 256 -> A section (global row Mtile0+row); else B section
  // (global row Ntile0+row-256). per-lane source col pre-swizzled:
  // logical 16B slot = (lane&3) ^ ((row>>1)&3) = (lane&3) ^ ((lane>>3)&3).
  const unsigned short* gsrc[6];
  #pragma unroll
  for (int i = 0; i < 6; ++i) {
    const int rowc = w * 96 + i * 16;             // chunk base row in slot
    const int row = rowc + (lane >> 2);
    const unsigned short* g = (rowc < 256)
        ? (A + ((size_t)(Mtile0 + row) << 10))
        : (B + ((size_t)(Ntile0 + row - 256) << 10));
    gsrc[i] = g + (((lane & 3) ^ ((lane >> 3) & 3)) << 3);
  }

  f32x4 acc[8][4];
  #pragma unroll
  for (int i = 0; i < 8; ++i)
    #pragma unroll
    for (int j = 0; j < 4; ++j) acc[i][j] = (f32x4){0.f, 0.f, 0.f, 0.f};

  // prologue: stage regions 0 -> slot 0, 1 -> slot 1; wait region 0
  K2_STAGE6(0)
  K2_STAGE6(1)
  K2_VM6;
  __builtin_amdgcn_s_barrier();
  __builtin_amdgcn_sched_barrier(0);

  // phases 0..29: read slot p%3, stage region p+2 -> slot (p+2)%3
  #pragma unroll 1
  for (int it = 0; it < 10; ++it) {
    K2_PHASE(0, 2, true, K2_VM6, true)
    K2_PHASE(1, 0, true, K2_VM6, true)
    K2_PHASE(2, 1, true, K2_VM6, true)
  }
  // phase 30 (slot 0): no stage; drain to region 31
  K2_PHASE(0, 2, false, K2_VM0, true)
  // phase 31 (slot 1): last compute, no sync needed before epilogue
  K2_PHASE(1, 2, false, (void)0, false)

  // epilogue: D rows = delta (i = d1d2), cols = S rows (bl, r)
  const int col0 = Ntile0 + (wn << 6) + c15;
  const int rowb = Mtile0 + (wm << 7);
  #pragma unroll
  for (int nt = 0; nt < 4; ++nt) {
    const int n = col0 + (nt << 4);
    const int bl = n / 10;
    const int r = n - bl * 10;
    char* dst = (r < 8)
        ? (char*)U2a + (size_t)bl * 16384 + (size_t)r * 8
        : (char*)U2b + (size_t)bl * 4096 + (size_t)(r - 8) * 8;
    const int rbs = (r < 8) ? 64 : 16;
    #pragma unroll
    for (int mt = 0; mt < 8; ++mt) {
      const int mp = (rowb + (mt << 4) + (quad << 2)) >> 2;   // delta>>2
      uint2 v;
      v.x = pack2(acc[mt][nt][0], acc[mt][nt][1]);
      v.y = pack2(acc[mt][nt][2], acc[mt][nt][3]);
      *(uint2*)(dst + (size_t)mp * rbs) = v;
    }
  }
}

// ---------------- K3: output sweep (R21: in-place 20 KB, plain stores) -----
// Single buffer: stage 0 writes cross wave slices (one barrier); stages 1-4
// read+write only the wave's own 64-row slice IN PLACE (reads issue before
// writes; same-wave DS ordering; validated by R21's measured pass).
// Epilogue: plain f32 partial stores — each oidx written exactly once per
// block (u=0..63 x i,c15 covers 1024).
__global__ __launch_bounds__(256, 4) void k3_outsweep(
    const unsigned short* __restrict__ U2a, const unsigned short* __restrict__ U2b,
    const unsigned short* __restrict__ bf3, const unsigned short* __restrict__ bf3l,
    float* __restrict__ Up) {              // [5120][1024] f32 partials
  __shared__ __align__(16) unsigned short st[10240];   // 20480 B in-place
  const int t = threadIdx.x, bx = blockIdx.x;
  const int L = bx - (bx / 10) * 10;
  const int lane = t & 63, w = t >> 6;
  const int c15 = lane & 15, quad = lane >> 4;
  int ddv[3], sv[3];
  #pragma unroll
  for (int nt = 0; nt < 3; ++nt) {
    int n = nt * 16 + c15; ddv[nt] = n / 12; sv[nt] = n - ddv[nt] * 12;
  }
  f32x4 acc[4][3];
  // ---- stage 0: A-frags from global U2 (coalesced), cores (0,1) -> st ----
  {
    short8 bfr[3][2];
    #pragma unroll
    for (int nt = 0; nt < 3; ++nt) {
      bfr[nt][0] = *(const short8*)&bf3[(nt * 2 + 0) * 512 + lane * 8];
      bfr[nt][1] = *(const short8*)&bf3[(nt * 2 + 1) * 512 + lane * 8];
    }
    const char* Ua = (const char*)U2a + (size_t)bx * 16384;
    const char* Ub = (const char*)U2b + (size_t)bx * 4096;
    #pragma unroll
    for (int rt = 0; rt < 4; ++rt) {
      const int m = w * 64 + rt * 16 + c15;
      const short8 a0 = *(const short8*)(Ua + m * 64 + quad * 16);
      const short8 a1 = *(const short8*)(Ub + m * 16);   // quads 1-3: k>=40, B=0
      #pragma unroll
      for (int nt = 0; nt < 3; ++nt) {
        f32x4 a = {0.f, 0.f, 0.f, 0.f};
        a = __builtin_amdgcn_mfma_f32_16x16x32_bf16(a0, bfr[nt][0], a, 0, 0, 0);
        a = __builtin_amdgcn_mfma_f32_16x16x32_bf16(a1, bfr[nt][1], a, 0, 0, 0);
        acc[rt][nt] = a;
      }
    }
    stage_writes80<0, false>(st, acc, w, quad, ddv, sv);
  }
  __syncthreads();   // stage 0 writes cross wave slices — the ONE barrier
  // stage 1: in-place (own-slice reads fully issued before own-slice writes)
  mfma_stage80(st, bf3 + 1 * 3072, w, lane, c15, quad, acc);
  stage_writes80<1, false>(st, acc, w, quad, ddv, sv);
  // stage 2: in-place
  mfma_stage80(st, bf3 + 2 * 3072, w, lane, c15, quad, acc);
  stage_writes80<2, false>(st, acc, w, quad, ddv, sv);
  // stage 3: in-place
  mfma_stage80(st, bf3 + 3 * 3072, w, lane, c15, quad, acc);
  stage_writes80<3, false>(st, acc, w, quad, ddv, sv);
  // ---- stage 4: cores (8,9) + ring trace from st -> Up[bx] ---------------
  {
    const unsigned short* Bf = bf3l + L * 1024;
    const short8 b0 = *(const short8*)&Bf[lane * 8];
    const short8 b1 = *(const short8*)&Bf[512 + lane * 8];
    #pragma unroll
    for (int rt = 0; rt < 4; ++rt) {
      const int rowA = w * 64 + rt * 16 + c15;
      const short8 a0 = *(const short8*)((const char*)st + rowA * 80 + quad * 16);
      const int a1off = rowA * 80 + ((quad == 0) ? 64 : 0);
      const short8 a1 = *(const short8*)((const char*)st + a1off);
      f32x4 a = {0.f, 0.f, 0.f, 0.f};
      a = __builtin_amdgcn_mfma_f32_16x16x32_bf16(a0, b0, a, 0, 0, 0);
      a = __builtin_amdgcn_mfma_f32_16x16x32_bf16(a1, b1, a, 0, 0, 0);
      if (c15 < 4) {
        const int u = w * 16 + rt * 4 + quad;
        #pragma unroll
        for (int i = 0; i < 4; ++i) {
          const int oidx = u * 16 + i * 4 + c15;   // p'1..p'10
          Up[((size_t)bx << 10) + oidx] = a[i];
        }
      }
    }
  }
}

// ---------------- K4: f64 reduce of 10 L-partials + bias -> out -------------
// f64 accumulation: ulp(1e13) ~ 2e-3 -> exact sum of partials, no ordering
// jitter, no systematic rounding. Deterministic across graph replays.
__global__ __launch_bounds__(256) void k4_reduce(
    const float* __restrict__ Up, const float* __restrict__ bias,
    float* __restrict__ out) {
  const int idx = blockIdx.x * 256 + threadIdx.x;   // 0..524287
  const int o = idx & 1023;
  const int b = idx >> 10;
  const float* p = Up + ((size_t)(b * 10) << 10) + o;
  double s = 0.0;
  #pragma unroll
  for (int L = 0; L < 10; ++L) s += (double)p[(size_t)L << 10];
  s += (double)bias[o];
  out[idx] = (float)s;
}

// ---------------- launch ----------------------------------------------------
extern "C" void kernel_launch(void* const* d_in, const int* in_sizes, int n_in,
                              void* d_out, int out_size, void* d_ws, size_t ws_size,
                              hipStream_t stream) {
  (void)in_sizes; (void)n_in; (void)ws_size; (void)out_size;
  const float* x    = (const float*)d_in[0];
  const float* ic   = (const float*)d_in[1];
  const float* oc   = (const float*)d_in[2];
  const float* cc   = (const float*)d_in[3];
  const float* bias = (const float*)d_in[4];
  float* out = (float*)d_out;

  char* ws = (char*)d_ws;
  unsigned short* S    = (unsigned short*)(ws);              // 104857600 B
  unsigned short* U2a  = (unsigned short*)(ws + 104857600);  //  83886080 B
  unsigned short* U2b  = (unsigned short*)(ws + 188743680);  //  20971520 B
  unsigned short* Bt   = (unsigned short*)(ws + 209715200);  //   2097152 B
  float*          c2x  = (float*)(ws + 211812352);           //      6400 B
  unsigned short* bf1  = (unsigned short*)(ws + 211818752);  //     24576 B
  unsigned short* bf3  = (unsigned short*)(ws + 211843328);  //     24576 B
  unsigned short* bf3l = (unsigned short*)(ws + 211867904);  //     20480 B
  // Up reuses the S region (S fully consumed by k2 before k3 runs):
  float*          Up   = (float*)(ws);                       //  20971520 B

  k0_prep<<<1028, 256, 0, stream>>>(ic, oc, cc, Bt, c2x, bf1, bf3, bf3l);
  k1_insweep<<<5120, 256, 0, stream>>>(x, c2x, bf1, S);
  k2_gemm<<<1600, 256, 0, stream>>>(Bt, S, U2a, U2b);
  k3_outsweep<<<5120, 256, 0, stream>>>(U2a, U2b, bf3, bf3l, Up);
  k4_reduce<<<2048, 256, 0, stream>>>(Up, bias, out);
}